// Round 2
// baseline (230.521 us; speedup 1.0000x reference)
//
#include <hip/hip_runtime.h>
#include <math.h>

#define N_NODES 50000
#define N_EDGES 400000
#define N_TOT   450000   /* edges + self-loops */
#define NEG 0.2f
#define CAP 64           /* edge bucket capacity; deg = Poisson(8)+1, max over dataset ~27 */

typedef __attribute__((ext_vector_type(8))) short bf16x8;
typedef __attribute__((ext_vector_type(8))) unsigned short u16x8;
typedef __attribute__((ext_vector_type(4))) float f32x4;

__device__ __forceinline__ float lrelu(float x) { return x > 0.f ? x : NEG * x; }

__device__ __forceinline__ unsigned short f2bf(float f) {
    unsigned u = __float_as_uint(f);
    unsigned r = u + 0x7FFFu + ((u >> 16) & 1u);   /* RNE */
    return (unsigned short)(r >> 16);
}
__device__ __forceinline__ float bf2f(unsigned short h) {
    return __uint_as_float(((unsigned)h) << 16);
}

/* ---------------- init: weight prep (W1/W2 hi, W1a hi+lo) + cursor zero ---------------- */
__global__ void k_init(const float* __restrict__ W1, unsigned short* W1hiT,
                       const float* __restrict__ W2, unsigned short* W2hiT,
                       const float* __restrict__ a1s, const float* __restrict__ a1d,
                       unsigned short* W1aThi, unsigned short* W1aTlo,
                       int* cursor) {
    int i = blockIdx.x * 256 + threadIdx.x;
    if (i < 128 * 512) {
        int col = i & 511, k = i >> 9;
        W1hiT[col * 128 + k] = f2bf(W1[k * 512 + col]);
    } else if (i < 128 * 512 + 512 * 16) {
        int j = i - 128 * 512;
        int col = j & 15, k = j >> 4;
        W2hiT[col * 512 + k] = f2bf(W2[k * 16 + col]);
    } else if (i < 128 * 512 + 512 * 16 + 128 * 16) {
        int j = i - (128 * 512 + 512 * 16);
        int c16 = j & 15, k = j >> 4;
        int hd = c16 & 7;
        const float* av = (c16 < 8) ? a1s : a1d;
        float acc = 0.f;
#pragma unroll 8
        for (int c = 0; c < 64; c++)
            acc = fmaf(W1[k * 512 + hd * 64 + c], av[hd * 64 + c], acc);
        unsigned short h = f2bf(acc);
        W1aThi[c16 * 128 + k] = h;
        W1aTlo[c16 * 128 + k] = f2bf(acc - bf2f(h));
    } else {
        int j = i - (128 * 512 + 512 * 16 + 128 * 16);
        if (j < N_NODES) cursor[j] = 0;
    }
}

/* ---------------- merged: edge scatter-append (blocks < SCAT) + layer-1 GEMM ---------------- */
#define SCAT 256
__global__ __launch_bounds__(256) void k_sg1(const int* __restrict__ ei,
                                             int* __restrict__ cursor,
                                             int* __restrict__ colsrc,
                                             const float* __restrict__ x,
                                             const unsigned short* __restrict__ W1hiT,
                                             const unsigned short* __restrict__ W1aThi,
                                             const unsigned short* __restrict__ W1aTlo,
                                             unsigned short* __restrict__ h1b,
                                             float* __restrict__ al1s,
                                             float* __restrict__ al1d) {
    __shared__ unsigned short xs_hi[64 * 136];
    if (blockIdx.x < SCAT) {
        int gtid = blockIdx.x * 256 + threadIdx.x;
        for (int i = gtid; i < N_TOT; i += SCAT * 256) {
            int src, dst;
            if (i < N_EDGES) { src = ei[i]; dst = ei[N_EDGES + i]; }
            else             { src = dst = i - N_EDGES; }
            int pos = atomicAdd(&cursor[dst], 1);
            if (pos < CAP) colsrc[dst * CAP + pos] = src;
        }
        return;
    }
    const int t = threadIdx.x;
    const int rb = (blockIdx.x - SCAT) * 64;

#pragma unroll
    for (int i = 0; i < 8; i++) {
        int idx = t + 256 * i;           /* 2048 float4 total */
        int r = idx >> 5;                /* 32 float4 per row */
        int k = (idx & 31) * 4;
        int gr = rb + r;
        float4 v = make_float4(0.f, 0.f, 0.f, 0.f);
        if (gr < N_NODES) v = *reinterpret_cast<const float4*>(&x[gr * 128 + k]);
        ushort4 hi;
        hi.x = f2bf(v.x); hi.y = f2bf(v.y); hi.z = f2bf(v.z); hi.w = f2bf(v.w);
        *reinterpret_cast<ushort4*>(&xs_hi[r * 136 + k]) = hi;
    }
    __syncthreads();

    const int lane = t & 63;
    const int w = t >> 6;
    const int kbase = (lane >> 4) * 8;
    const int colloc = (w << 4) + (lane & 15);

#pragma unroll
    for (int pr = 0; pr < 4; pr++) {
        bf16x8 bhi[2][4];
#pragma unroll
        for (int si = 0; si < 2; si++) {
            int col = (pr * 2 + si) * 64 + colloc;
#pragma unroll
            for (int kc = 0; kc < 4; kc++)
                bhi[si][kc] = *reinterpret_cast<const bf16x8*>(&W1hiT[col * 128 + kc * 32 + kbase]);
        }
#pragma unroll
        for (int mt = 0; mt < 4; mt++) {
            const int arow = mt * 16 + (lane & 15);
            bf16x8 ah[4];
#pragma unroll
            for (int kc = 0; kc < 4; kc++)
                ah[kc] = *reinterpret_cast<const bf16x8*>(&xs_hi[arow * 136 + kc * 32 + kbase]);
#pragma unroll
            for (int si = 0; si < 2; si++) {
                f32x4 acc = {0.f, 0.f, 0.f, 0.f};
#pragma unroll
                for (int kc = 0; kc < 4; kc++)
                    acc = __builtin_amdgcn_mfma_f32_16x16x32_bf16(ah[kc], bhi[si][kc], acc, 0, 0, 0);
                const int col = (pr * 2 + si) * 64 + colloc;
                const int r0 = rb + mt * 16 + (lane >> 4) * 4;
#pragma unroll
                for (int r = 0; r < 4; r++) {
                    int row = r0 + r;
                    if (row < N_NODES) h1b[row * 512 + col] = f2bf(acc[r]);
                }
            }
        }
    }

    /* fused attention-half tile: wave w handles m-tile w, cols 0..15 of W1a (hi+lo) */
    {
        const int c16 = lane & 15;
        bf16x8 bh[4], bl[4];
#pragma unroll
        for (int kc = 0; kc < 4; kc++) {
            bh[kc] = *reinterpret_cast<const bf16x8*>(&W1aThi[c16 * 128 + kc * 32 + kbase]);
            bl[kc] = *reinterpret_cast<const bf16x8*>(&W1aTlo[c16 * 128 + kc * 32 + kbase]);
        }
        const int arow = (w << 4) + (lane & 15);
        f32x4 acc = {0.f, 0.f, 0.f, 0.f};
#pragma unroll
        for (int kc = 0; kc < 4; kc++) {
            bf16x8 ah = *reinterpret_cast<const bf16x8*>(&xs_hi[arow * 136 + kc * 32 + kbase]);
            acc = __builtin_amdgcn_mfma_f32_16x16x32_bf16(ah, bh[kc], acc, 0, 0, 0);
            acc = __builtin_amdgcn_mfma_f32_16x16x32_bf16(ah, bl[kc], acc, 0, 0, 0);
        }
        const int r0 = rb + (w << 4) + (lane >> 4) * 4;
#pragma unroll
        for (int r = 0; r < 4; r++) {
            int row = r0 + r;
            if (row < N_NODES) {
                if (c16 < 8) al1s[row * 8 + c16] = acc[r];
                else         al1d[row * 8 + (c16 - 8)] = acc[r];
            }
        }
    }
}

/* ---------------- Layer 1 softmax+agg FUSED with layer-2 GEMM ----------------
   512 threads = 8 waves; 2 waves per dst node (4 nodes/block).
   Each wave owns 256 channels (half = wv&1); lane owns 4 channels (8B loads).
   Gather: unroll-8 groups, cnt rounded up to x8 with zero-weight padding
   (pad lanes read h1b row 0 -> L2-hot, no HBM cost) so all 8 loads issue
   unconditionally -> 8-deep MLP.
   Epilogue: 4 finished rows -> LDS bf16, wave 0 does 4x512 @ 512x16 via MFMA,
   emits h2b + al2s/al2d. h1a never touches HBM. */
__global__ __launch_bounds__(512) void k_agg1(const int* __restrict__ cursor,
                                              const int* __restrict__ colsrc,
                                              const float* __restrict__ al1s,
                                              const float* __restrict__ al1d,
                                              const unsigned short* __restrict__ h1b,
                                              const float* __restrict__ b1,
                                              const unsigned short* __restrict__ W2hiT,
                                              const float* __restrict__ a2s,
                                              const float* __restrict__ a2d,
                                              unsigned short* __restrict__ h2b,
                                              float* __restrict__ al2s,
                                              float* __restrict__ al2d) {
    __shared__ float pw[4][8 * 66];                      /* per-node edge weights, head-major */
    __shared__ __align__(16) unsigned short vs[4 * 520]; /* 4 finished h1 rows, bf16, padded  */
    const int wv   = threadIdx.x >> 6;                   /* 0..7 */
    const int lane = threadIdx.x & 63;
    const int nd   = wv >> 1;                            /* node slot 0..3 */
    const int half = wv & 1;                             /* channel half 0/1 */
    const int n0 = blockIdx.x * 4;
    const int n  = n0 + nd;                              /* grid exact */
    const int cnt = min(cursor[n], CAP);
    const int eb = n * CAP;
    const int h  = half * 4 + (lane >> 4);               /* lane's head */
    const int c4 = half * 256 + lane * 4;                /* first of 4 owned channels */
    float* mypw = pw[nd];

    const float4 dh = *reinterpret_cast<const float4*>(&al1d[n * 8 + half * 4]);

    int s0 = 0;
    float p0 = 0.f, p1 = 0.f, p2 = 0.f, p3 = 0.f;
    if (lane < cnt) {
        s0 = colsrc[eb + lane];
        const float4 u = *reinterpret_cast<const float4*>(&al1s[s0 * 8 + half * 4]);
        p0 = __expf(fminf(lrelu(u.x + dh.x), 60.f));
        p1 = __expf(fminf(lrelu(u.y + dh.y), 60.f));
        p2 = __expf(fminf(lrelu(u.z + dh.z), 60.f));
        p3 = __expf(fminf(lrelu(u.w + dh.w), 60.f));
    }
    mypw[(half * 4 + 0) * 66 + lane] = p0;
    mypw[(half * 4 + 1) * 66 + lane] = p1;
    mypw[(half * 4 + 2) * 66 + lane] = p2;
    mypw[(half * 4 + 3) * 66 + lane] = p3;

    float acc0 = 0.f, acc1 = 0.f, acc2 = 0.f, acc3 = 0.f, sm = 0.f;
    const int pwh = h * 66;
    const int cnt8 = (cnt + 7) & ~7;

    for (int j = 0; j < cnt8; j += 8) {
        int s[8]; float w[8]; ushort4 vv[8];
#pragma unroll
        for (int k = 0; k < 8; k++) {
            s[k] = __shfl(s0, j + k, 64);
            w[k] = mypw[pwh + j + k];
        }
#pragma unroll
        for (int k = 0; k < 8; k++)
            vv[k] = *reinterpret_cast<const ushort4*>(&h1b[s[k] * 512 + c4]);
#pragma unroll
        for (int k = 0; k < 8; k++) {
            sm += w[k];
            acc0 = fmaf(w[k], bf2f(vv[k].x), acc0);
            acc1 = fmaf(w[k], bf2f(vv[k].y), acc1);
            acc2 = fmaf(w[k], bf2f(vv[k].z), acc2);
            acc3 = fmaf(w[k], bf2f(vv[k].w), acc3);
        }
    }

    const float inv = 1.f / sm;
    const float4 bb = *reinterpret_cast<const float4*>(&b1[c4]);
    float v0 = acc0 * inv + bb.x;
    float v1 = acc1 * inv + bb.y;
    float v2 = acc2 * inv + bb.z;
    float v3 = acc3 * inv + bb.w;
    v0 = v0 > 0.f ? v0 : __expf(v0) - 1.f;
    v1 = v1 > 0.f ? v1 : __expf(v1) - 1.f;
    v2 = v2 > 0.f ? v2 : __expf(v2) - 1.f;
    v3 = v3 > 0.f ? v3 : __expf(v3) - 1.f;
    ushort4 o;
    o.x = f2bf(v0); o.y = f2bf(v1); o.z = f2bf(v2); o.w = f2bf(v3);
    *reinterpret_cast<ushort4*>(&vs[nd * 520 + c4]) = o;

    __syncthreads();

    if (wv == 0) {
        /* 4x512 @ 512x16 matvec for the block's 4 nodes via MFMA.
           A rows wrapped lane&3: rows 4-15 duplicate rows 0-3; their C rows are discarded. */
        const int col   = lane & 15;
        const int kbase = (lane >> 4) << 3;
        const int rowm  = lane & 3;
        f32x4 a2 = {0.f, 0.f, 0.f, 0.f};
#pragma unroll 4
        for (int kc = 0; kc < 16; kc++) {
            bf16x8 bh = *reinterpret_cast<const bf16x8*>(&W2hiT[col * 512 + kc * 32 + kbase]);
            bf16x8 ah = *reinterpret_cast<const bf16x8*>(&vs[rowm * 520 + kc * 32 + kbase]);
            a2 = __builtin_amdgcn_mfma_f32_16x16x32_bf16(ah, bh, a2, 0, 0, 0);
        }
        /* C: row=(lane>>4)*4+r, col=lane&15 -> lanes 0-15 hold rows 0-3 (the 4 nodes) */
        if (lane < 16) {
            const float as_c = a2s[col];
            const float ad_c = a2d[col];
#pragma unroll
            for (int r = 0; r < 4; r++) {
                float ps = a2[r] * as_c;
                float pd = a2[r] * ad_c;
                ps += __shfl_xor(ps, 1, 64); pd += __shfl_xor(pd, 1, 64);
                ps += __shfl_xor(ps, 2, 64); pd += __shfl_xor(pd, 2, 64);
                ps += __shfl_xor(ps, 4, 64); pd += __shfl_xor(pd, 4, 64);
                ps += __shfl_xor(ps, 8, 64); pd += __shfl_xor(pd, 8, 64);
                h2b[(n0 + r) * 16 + col] = f2bf(a2[r]);
                if (lane == 0) { al2s[n0 + r] = ps; al2d[n0 + r] = pd; }
            }
        }
    }
}

/* ---------------- Layer 2 aggregation -> out (8-edge-parallel, 4B h2b loads) ---------------- */
__global__ __launch_bounds__(256) void k_agg2(const int* __restrict__ cursor,
                                              const int* __restrict__ colsrc,
                                              const float* __restrict__ al2s,
                                              const float* __restrict__ al2d,
                                              const unsigned short* __restrict__ h2b,
                                              const float* __restrict__ b2,
                                              float* __restrict__ out) {
    int wv = threadIdx.x >> 6, lane = threadIdx.x & 63;
    int n = blockIdx.x * 4 + wv;
    if (n >= N_NODES) return;
    int cnt = min(cursor[n], CAP);
    const int eb = n * CAP;
    float ald = al2d[n];
    int q = lane >> 3;            /* edge slot 0..7 */
    int c2 = (lane & 7) << 1;     /* channel pair base */
    float acc0 = 0.f, acc1 = 0.f, smL = 0.f;
    for (int e = q; e < cnt; e += 8) {
        int s = colsrc[eb + e];
        float w = __expf(fminf(lrelu(al2s[s] + ald), 60.f));
        unsigned v = *reinterpret_cast<const unsigned*>(&h2b[s * 16 + c2]);
        smL += w;
        acc0 = fmaf(w, bf2f((unsigned short)(v & 0xFFFFu)), acc0);
        acc1 = fmaf(w, __uint_as_float(v & 0xFFFF0000u), acc1);
    }
    acc0 += __shfl_xor(acc0, 8, 64);  acc1 += __shfl_xor(acc1, 8, 64);  smL += __shfl_xor(smL, 8, 64);
    acc0 += __shfl_xor(acc0, 16, 64); acc1 += __shfl_xor(acc1, 16, 64); smL += __shfl_xor(smL, 16, 64);
    acc0 += __shfl_xor(acc0, 32, 64); acc1 += __shfl_xor(acc1, 32, 64); smL += __shfl_xor(smL, 32, 64);
    if (q == 0) {
        float inv = 1.f / smL;
        float2 r;
        r.x = acc0 * inv + b2[c2];
        r.y = acc1 * inv + b2[c2 + 1];
        *reinterpret_cast<float2*>(&out[n * 16 + c2]) = r;
    }
}

/* ---------------- launch ---------------- */
extern "C" void kernel_launch(void* const* d_in, const int* in_sizes, int n_in,
                              void* d_out, int out_size, void* d_ws, size_t ws_size,
                              hipStream_t stream) {
    const float* x   = (const float*)d_in[0];
    const int*   ei  = (const int*)d_in[1];
    const float* W1  = (const float*)d_in[2];
    const float* a1s = (const float*)d_in[3];
    const float* a1d = (const float*)d_in[4];
    const float* b1  = (const float*)d_in[5];
    const float* W2  = (const float*)d_in[6];
    const float* a2s = (const float*)d_in[7];
    const float* a2d = (const float*)d_in[8];
    const float* b2  = (const float*)d_in[9];
    float* out = (float*)d_out;

    char* ws = (char*)d_ws;
    unsigned short* h1b = (unsigned short*)(ws + 0);            /* N*512 bf16 = 51.2 MB */
    unsigned short* h2b = (unsigned short*)(ws + 102400000);    /* N*16 bf16 = 1.6 MB */
    float* al1s = (float*)(ws + 105600000);    /* N*8 */
    float* al1d = (float*)(ws + 107200000);    /* N*8 */
    float* al2s = (float*)(ws + 108800000);    /* N */
    float* al2d = (float*)(ws + 109000000);    /* N */
    int* cursor = (int*)(ws + 109200000);      /* N ints */
    int* colsrc = (int*)(ws + 109400000);      /* N*CAP ints = 12.8 MB */
    unsigned short* W1hiT  = (unsigned short*)(ws + 122200000); /* 512x128 bf16 */
    unsigned short* W2hiT  = (unsigned short*)(ws + 122336000); /* 16x512 bf16 */
    unsigned short* W1aThi = (unsigned short*)(ws + 122352384); /* 16x128 bf16 */
    unsigned short* W1aTlo = (unsigned short*)(ws + 122356480);

    /* init: weight prep + cursor zero (one launch) */
    k_init<<<492, 256, 0, stream>>>(W1, W1hiT, W2, W2hiT, a1s, a1d, W1aThi, W1aTlo, cursor);

    /* scatter-append + layer-1 GEMM (merged) */
    k_sg1<<<SCAT + (N_NODES + 63) / 64, 256, 0, stream>>>(ei, cursor, colsrc, x,
                                                          W1hiT, W1aThi, W1aTlo,
                                                          h1b, al1s, al1d);

    /* layer 1 aggregation fused with layer-2 GEMM (2 waves/node, unroll-8) */
    k_agg1<<<(N_NODES + 3) / 4, 512, 0, stream>>>(cursor, colsrc, al1s, al1d, h1b, b1,
                                                  W2hiT, a2s, a2d, h2b, al2s, al2d);

    /* layer 2 aggregation */
    k_agg2<<<(N_NODES + 3) / 4, 256, 0, stream>>>(cursor, colsrc, al2s, al2d, h2b, b2, out);
}

// Round 3
// 223.116 us; speedup vs baseline: 1.0332x; 1.0332x over previous
//
#include <hip/hip_runtime.h>
#include <math.h>

#define N_NODES 50000
#define N_EDGES 400000
#define N_TOT   450000   /* edges + self-loops */
#define NEG 0.2f
#define CAP 64           /* edge bucket capacity; deg = Poisson(8)+1, max over dataset ~27 */

typedef __attribute__((ext_vector_type(8))) short bf16x8;
typedef __attribute__((ext_vector_type(8))) unsigned short u16x8;
typedef __attribute__((ext_vector_type(4))) float f32x4;

__device__ __forceinline__ float lrelu(float x) { return x > 0.f ? x : NEG * x; }

__device__ __forceinline__ unsigned short f2bf(float f) {
    unsigned u = __float_as_uint(f);
    unsigned r = u + 0x7FFFu + ((u >> 16) & 1u);   /* RNE */
    return (unsigned short)(r >> 16);
}
__device__ __forceinline__ float bf2f(unsigned short h) {
    return __uint_as_float(((unsigned)h) << 16);
}

/* ---------------- init: weight prep (W1/W2 hi, W1a hi+lo) + cursor zero ---------------- */
__global__ void k_init(const float* __restrict__ W1, unsigned short* W1hiT,
                       const float* __restrict__ W2, unsigned short* W2hiT,
                       const float* __restrict__ a1s, const float* __restrict__ a1d,
                       unsigned short* W1aThi, unsigned short* W1aTlo,
                       int* cursor) {
    int i = blockIdx.x * 256 + threadIdx.x;
    if (i < 128 * 512) {
        int col = i & 511, k = i >> 9;
        W1hiT[col * 128 + k] = f2bf(W1[k * 512 + col]);
    } else if (i < 128 * 512 + 512 * 16) {
        int j = i - 128 * 512;
        int col = j & 15, k = j >> 4;
        W2hiT[col * 512 + k] = f2bf(W2[k * 16 + col]);
    } else if (i < 128 * 512 + 512 * 16 + 128 * 16) {
        int j = i - (128 * 512 + 512 * 16);
        int c16 = j & 15, k = j >> 4;
        int hd = c16 & 7;
        const float* av = (c16 < 8) ? a1s : a1d;
        float acc = 0.f;
#pragma unroll 8
        for (int c = 0; c < 64; c++)
            acc = fmaf(W1[k * 512 + hd * 64 + c], av[hd * 64 + c], acc);
        unsigned short h = f2bf(acc);
        W1aThi[c16 * 128 + k] = h;
        W1aTlo[c16 * 128 + k] = f2bf(acc - bf2f(h));
    } else {
        int j = i - (128 * 512 + 512 * 16 + 128 * 16);
        if (j < N_NODES) cursor[j] = 0;
    }
}

/* ---------------- merged: edge scatter-append (blocks < SCAT) + layer-1 GEMM ---------------- */
#define SCAT 256
__global__ __launch_bounds__(256) void k_sg1(const int* __restrict__ ei,
                                             int* __restrict__ cursor,
                                             int* __restrict__ colsrc,
                                             const float* __restrict__ x,
                                             const unsigned short* __restrict__ W1hiT,
                                             const unsigned short* __restrict__ W1aThi,
                                             const unsigned short* __restrict__ W1aTlo,
                                             unsigned short* __restrict__ h1b,
                                             float* __restrict__ al1s,
                                             float* __restrict__ al1d) {
    __shared__ unsigned short xs_hi[64 * 136];
    if (blockIdx.x < SCAT) {
        int gtid = blockIdx.x * 256 + threadIdx.x;
        for (int i = gtid; i < N_TOT; i += SCAT * 256) {
            int src, dst;
            if (i < N_EDGES) { src = ei[i]; dst = ei[N_EDGES + i]; }
            else             { src = dst = i - N_EDGES; }
            int pos = atomicAdd(&cursor[dst], 1);
            if (pos < CAP) colsrc[dst * CAP + pos] = src;
        }
        return;
    }
    const int t = threadIdx.x;
    const int rb = (blockIdx.x - SCAT) * 64;

#pragma unroll
    for (int i = 0; i < 8; i++) {
        int idx = t + 256 * i;           /* 2048 float4 total */
        int r = idx >> 5;                /* 32 float4 per row */
        int k = (idx & 31) * 4;
        int gr = rb + r;
        float4 v = make_float4(0.f, 0.f, 0.f, 0.f);
        if (gr < N_NODES) v = *reinterpret_cast<const float4*>(&x[gr * 128 + k]);
        ushort4 hi;
        hi.x = f2bf(v.x); hi.y = f2bf(v.y); hi.z = f2bf(v.z); hi.w = f2bf(v.w);
        *reinterpret_cast<ushort4*>(&xs_hi[r * 136 + k]) = hi;
    }
    __syncthreads();

    const int lane = t & 63;
    const int w = t >> 6;
    const int kbase = (lane >> 4) * 8;
    const int colloc = (w << 4) + (lane & 15);

#pragma unroll
    for (int pr = 0; pr < 4; pr++) {
        bf16x8 bhi[2][4];
#pragma unroll
        for (int si = 0; si < 2; si++) {
            int col = (pr * 2 + si) * 64 + colloc;
#pragma unroll
            for (int kc = 0; kc < 4; kc++)
                bhi[si][kc] = *reinterpret_cast<const bf16x8*>(&W1hiT[col * 128 + kc * 32 + kbase]);
        }
#pragma unroll
        for (int mt = 0; mt < 4; mt++) {
            const int arow = mt * 16 + (lane & 15);
            bf16x8 ah[4];
#pragma unroll
            for (int kc = 0; kc < 4; kc++)
                ah[kc] = *reinterpret_cast<const bf16x8*>(&xs_hi[arow * 136 + kc * 32 + kbase]);
#pragma unroll
            for (int si = 0; si < 2; si++) {
                f32x4 acc = {0.f, 0.f, 0.f, 0.f};
#pragma unroll
                for (int kc = 0; kc < 4; kc++)
                    acc = __builtin_amdgcn_mfma_f32_16x16x32_bf16(ah[kc], bhi[si][kc], acc, 0, 0, 0);
                const int col = (pr * 2 + si) * 64 + colloc;
                const int r0 = rb + mt * 16 + (lane >> 4) * 4;
#pragma unroll
                for (int r = 0; r < 4; r++) {
                    int row = r0 + r;
                    if (row < N_NODES) h1b[row * 512 + col] = f2bf(acc[r]);
                }
            }
        }
    }

    /* fused attention-half tile: wave w handles m-tile w, cols 0..15 of W1a (hi+lo) */
    {
        const int c16 = lane & 15;
        bf16x8 bh[4], bl[4];
#pragma unroll
        for (int kc = 0; kc < 4; kc++) {
            bh[kc] = *reinterpret_cast<const bf16x8*>(&W1aThi[c16 * 128 + kc * 32 + kbase]);
            bl[kc] = *reinterpret_cast<const bf16x8*>(&W1aTlo[c16 * 128 + kc * 32 + kbase]);
        }
        const int arow = (w << 4) + (lane & 15);
        f32x4 acc = {0.f, 0.f, 0.f, 0.f};
#pragma unroll
        for (int kc = 0; kc < 4; kc++) {
            bf16x8 ah = *reinterpret_cast<const bf16x8*>(&xs_hi[arow * 136 + kc * 32 + kbase]);
            acc = __builtin_amdgcn_mfma_f32_16x16x32_bf16(ah, bh[kc], acc, 0, 0, 0);
            acc = __builtin_amdgcn_mfma_f32_16x16x32_bf16(ah, bl[kc], acc, 0, 0, 0);
        }
        const int r0 = rb + (w << 4) + (lane >> 4) * 4;
#pragma unroll
        for (int r = 0; r < 4; r++) {
            int row = r0 + r;
            if (row < N_NODES) {
                if (c16 < 8) al1s[row * 8 + c16] = acc[r];
                else         al1d[row * 8 + (c16 - 8)] = acc[r];
            }
        }
    }
}

/* ---------------- Layer 1 softmax+agg FUSED with layer-2 GEMM ----------------
   One wave per dst node (4/block, 256 thr). Lane owns 8 ch (one 16B load/edge).
   Gather: cnt padded to x4 (pad lanes: s0=0 -> row-0 L1-hot, weight 0),
   explicit PING-PONG double buffer: load group g+2 while consuming group g
   -> 8 loads in flight (round-1 compiler only kept 4: VGPR=32 proved it).
   Epilogue: 4 finished rows -> LDS bf16, wave 0 does 4x512 @ 512x16 via MFMA,
   emits h2b + al2s/al2d. h1a never touches HBM. */
__global__ __launch_bounds__(256) void k_agg1(const int* __restrict__ cursor,
                                              const int* __restrict__ colsrc,
                                              const float* __restrict__ al1s,
                                              const float* __restrict__ al1d,
                                              const unsigned short* __restrict__ h1b,
                                              const float* __restrict__ b1,
                                              const unsigned short* __restrict__ W2hiT,
                                              const float* __restrict__ a2s,
                                              const float* __restrict__ a2d,
                                              unsigned short* __restrict__ h2b,
                                              float* __restrict__ al2s,
                                              float* __restrict__ al2d) {
    __shared__ float pw[4][8 * 66];                      /* per-wave edge weights, head-major */
    __shared__ __align__(16) unsigned short vs[4 * 520]; /* 4 finished h1 rows, bf16, padded  */
    const int wid  = threadIdx.x >> 6;
    const int lane = threadIdx.x & 63;
    const int n0 = blockIdx.x * 4;
    const int n  = n0 + wid;                             /* grid exact: n < N_NODES always */
    const int cnt = min(cursor[n], CAP);
    const int eb = n * CAP;
    const int h  = lane >> 3;                            /* head owned by this lane */
    const int c8 = lane << 3;                            /* first of 8 owned channels */
    float* mypw = pw[wid];

    const float4 d0 = *reinterpret_cast<const float4*>(&al1d[n * 8]);
    const float4 d1 = *reinterpret_cast<const float4*>(&al1d[n * 8 + 4]);

    int s0 = 0;
    float p[8];
    if (lane < cnt) {
        s0 = colsrc[eb + lane];
        const float4 u0 = *reinterpret_cast<const float4*>(&al1s[s0 * 8]);
        const float4 u1 = *reinterpret_cast<const float4*>(&al1s[s0 * 8 + 4]);
        p[0] = __expf(fminf(lrelu(u0.x + d0.x), 60.f));
        p[1] = __expf(fminf(lrelu(u0.y + d0.y), 60.f));
        p[2] = __expf(fminf(lrelu(u0.z + d0.z), 60.f));
        p[3] = __expf(fminf(lrelu(u0.w + d0.w), 60.f));
        p[4] = __expf(fminf(lrelu(u1.x + d1.x), 60.f));
        p[5] = __expf(fminf(lrelu(u1.y + d1.y), 60.f));
        p[6] = __expf(fminf(lrelu(u1.z + d1.z), 60.f));
        p[7] = __expf(fminf(lrelu(u1.w + d1.w), 60.f));
    } else {
#pragma unroll
        for (int hh = 0; hh < 8; hh++) p[hh] = 0.f;
        s0 = 0;                                          /* pad lanes gather row 0 (hot) */
    }
#pragma unroll
    for (int hh = 0; hh < 8; hh++) mypw[hh * 66 + lane] = p[hh];

    float acc[8] = {0.f, 0.f, 0.f, 0.f, 0.f, 0.f, 0.f, 0.f};
    float sm = 0.f;
    const int pwh = h * 66;
    const int cnt4 = (cnt + 3) & ~3;                     /* cnt>=1 (self-loop) -> cnt4>=4 */
    const int G = cnt4 >> 2;                             /* number of 4-edge groups */

    u16x8 vA[4], vB[4];                                  /* fixed-index only (no scratch) */

    auto LD = [&](u16x8* dst, int jj) {
#pragma unroll
        for (int k = 0; k < 4; k++) {
            int s = __shfl(s0, jj + k, 64);
            dst[k] = *reinterpret_cast<const u16x8*>(&h1b[s * 512 + c8]);
        }
    };
    auto CONS = [&](const u16x8* src, int jj) {
#pragma unroll
        for (int k = 0; k < 4; k++) {
            float w = mypw[pwh + jj + k];
            sm += w;
#pragma unroll
            for (int c = 0; c < 8; c++)
                acc[c] = fmaf(w, bf2f(src[k][c]), acc[c]);
        }
    };

    LD(vA, 0);
    if (G > 1) LD(vB, 4);
    int g = 0;
    for (; g + 2 < G; g += 2) {
        CONS(vA, g * 4);       LD(vA, (g + 2) * 4);
        CONS(vB, g * 4 + 4);   if (g + 3 < G) LD(vB, (g + 3) * 4);
    }
    if (g < G)     CONS(vA, g * 4);
    if (g + 1 < G) CONS(vB, g * 4 + 4);

    const float inv = 1.f / sm;
    const float4 ba = *reinterpret_cast<const float4*>(&b1[c8]);
    const float4 bb = *reinterpret_cast<const float4*>(&b1[c8 + 4]);
    float v[8];
    v[0] = acc[0] * inv + ba.x; v[1] = acc[1] * inv + ba.y;
    v[2] = acc[2] * inv + ba.z; v[3] = acc[3] * inv + ba.w;
    v[4] = acc[4] * inv + bb.x; v[5] = acc[5] * inv + bb.y;
    v[6] = acc[6] * inv + bb.z; v[7] = acc[7] * inv + bb.w;
#pragma unroll
    for (int k = 0; k < 8; k++)
        v[k] = v[k] > 0.f ? v[k] : __expf(v[k]) - 1.f;
    u16x8 o;
#pragma unroll
    for (int k = 0; k < 8; k++) o[k] = f2bf(v[k]);
    *reinterpret_cast<u16x8*>(&vs[wid * 520 + c8]) = o;

    __syncthreads();

    if (wid == 0) {
        /* 4x512 @ 512x16 matvec for the block's 4 nodes via MFMA.
           A rows wrapped lane&3: rows 4-15 duplicate rows 0-3; their C rows are discarded. */
        const int col   = lane & 15;
        const int kbase = (lane >> 4) << 3;
        const int rowm  = lane & 3;
        f32x4 a2 = {0.f, 0.f, 0.f, 0.f};
#pragma unroll 4
        for (int kc = 0; kc < 16; kc++) {
            bf16x8 bh = *reinterpret_cast<const bf16x8*>(&W2hiT[col * 512 + kc * 32 + kbase]);
            bf16x8 ah = *reinterpret_cast<const bf16x8*>(&vs[rowm * 520 + kc * 32 + kbase]);
            a2 = __builtin_amdgcn_mfma_f32_16x16x32_bf16(ah, bh, a2, 0, 0, 0);
        }
        /* C: row=(lane>>4)*4+r, col=lane&15 -> lanes 0-15 hold rows 0-3 (the 4 nodes) */
        if (lane < 16) {
            const float as_c = a2s[col];
            const float ad_c = a2d[col];
#pragma unroll
            for (int r = 0; r < 4; r++) {
                float ps = a2[r] * as_c;
                float pd = a2[r] * ad_c;
                ps += __shfl_xor(ps, 1, 64); pd += __shfl_xor(pd, 1, 64);
                ps += __shfl_xor(ps, 2, 64); pd += __shfl_xor(pd, 2, 64);
                ps += __shfl_xor(ps, 4, 64); pd += __shfl_xor(pd, 4, 64);
                ps += __shfl_xor(ps, 8, 64); pd += __shfl_xor(pd, 8, 64);
                h2b[(n0 + r) * 16 + col] = f2bf(a2[r]);
                if (lane == 0) { al2s[n0 + r] = ps; al2d[n0 + r] = pd; }
            }
        }
    }
}

/* ---------------- Layer 2 aggregation -> out (8-edge-parallel, 4B h2b loads) ---------------- */
__global__ __launch_bounds__(256) void k_agg2(const int* __restrict__ cursor,
                                              const int* __restrict__ colsrc,
                                              const float* __restrict__ al2s,
                                              const float* __restrict__ al2d,
                                              const unsigned short* __restrict__ h2b,
                                              const float* __restrict__ b2,
                                              float* __restrict__ out) {
    int wv = threadIdx.x >> 6, lane = threadIdx.x & 63;
    int n = blockIdx.x * 4 + wv;
    if (n >= N_NODES) return;
    int cnt = min(cursor[n], CAP);
    const int eb = n * CAP;
    float ald = al2d[n];
    int q = lane >> 3;            /* edge slot 0..7 */
    int c2 = (lane & 7) << 1;     /* channel pair base */
    float acc0 = 0.f, acc1 = 0.f, smL = 0.f;
    for (int e = q; e < cnt; e += 8) {
        int s = colsrc[eb + e];
        float w = __expf(fminf(lrelu(al2s[s] + ald), 60.f));
        unsigned v = *reinterpret_cast<const unsigned*>(&h2b[s * 16 + c2]);
        smL += w;
        acc0 = fmaf(w, bf2f((unsigned short)(v & 0xFFFFu)), acc0);
        acc1 = fmaf(w, __uint_as_float(v & 0xFFFF0000u), acc1);
    }
    acc0 += __shfl_xor(acc0, 8, 64);  acc1 += __shfl_xor(acc1, 8, 64);  smL += __shfl_xor(smL, 8, 64);
    acc0 += __shfl_xor(acc0, 16, 64); acc1 += __shfl_xor(acc1, 16, 64); smL += __shfl_xor(smL, 16, 64);
    acc0 += __shfl_xor(acc0, 32, 64); acc1 += __shfl_xor(acc1, 32, 64); smL += __shfl_xor(smL, 32, 64);
    if (q == 0) {
        float inv = 1.f / smL;
        float2 r;
        r.x = acc0 * inv + b2[c2];
        r.y = acc1 * inv + b2[c2 + 1];
        *reinterpret_cast<float2*>(&out[n * 16 + c2]) = r;
    }
}

/* ---------------- launch ---------------- */
extern "C" void kernel_launch(void* const* d_in, const int* in_sizes, int n_in,
                              void* d_out, int out_size, void* d_ws, size_t ws_size,
                              hipStream_t stream) {
    const float* x   = (const float*)d_in[0];
    const int*   ei  = (const int*)d_in[1];
    const float* W1  = (const float*)d_in[2];
    const float* a1s = (const float*)d_in[3];
    const float* a1d = (const float*)d_in[4];
    const float* b1  = (const float*)d_in[5];
    const float* W2  = (const float*)d_in[6];
    const float* a2s = (const float*)d_in[7];
    const float* a2d = (const float*)d_in[8];
    const float* b2  = (const float*)d_in[9];
    float* out = (float*)d_out;

    char* ws = (char*)d_ws;
    unsigned short* h1b = (unsigned short*)(ws + 0);            /* N*512 bf16 = 51.2 MB */
    unsigned short* h2b = (unsigned short*)(ws + 102400000);    /* N*16 bf16 = 1.6 MB */
    float* al1s = (float*)(ws + 105600000);    /* N*8 */
    float* al1d = (float*)(ws + 107200000);    /* N*8 */
    float* al2s = (float*)(ws + 108800000);    /* N */
    float* al2d = (float*)(ws + 109000000);    /* N */
    int* cursor = (int*)(ws + 109200000);      /* N ints */
    int* colsrc = (int*)(ws + 109400000);      /* N*CAP ints = 12.8 MB */
    unsigned short* W1hiT  = (unsigned short*)(ws + 122200000); /* 512x128 bf16 */
    unsigned short* W2hiT  = (unsigned short*)(ws + 122336000); /* 16x512 bf16 */
    unsigned short* W1aThi = (unsigned short*)(ws + 122352384); /* 16x128 bf16 */
    unsigned short* W1aTlo = (unsigned short*)(ws + 122356480);

    /* init: weight prep + cursor zero (one launch) */
    k_init<<<492, 256, 0, stream>>>(W1, W1hiT, W2, W2hiT, a1s, a1d, W1aThi, W1aTlo, cursor);

    /* scatter-append + layer-1 GEMM (merged) */
    k_sg1<<<SCAT + (N_NODES + 63) / 64, 256, 0, stream>>>(ei, cursor, colsrc, x,
                                                          W1hiT, W1aThi, W1aTlo,
                                                          h1b, al1s, al1d);

    /* layer 1 aggregation fused with layer-2 GEMM (ping-pong prefetch) */
    k_agg1<<<(N_NODES + 3) / 4, 256, 0, stream>>>(cursor, colsrc, al1s, al1d, h1b, b1,
                                                  W2hiT, a2s, a2d, h2b, al2s, al2d);

    /* layer 2 aggregation */
    k_agg2<<<(N_NODES + 3) / 4, 256, 0, stream>>>(cursor, colsrc, al2s, al2d, h2b, b2, out);
}

// Round 5
// 219.585 us; speedup vs baseline: 1.0498x; 1.0161x over previous
//
#include <hip/hip_runtime.h>
#include <math.h>

#define N_NODES 50000
#define N_EDGES 400000
#define N_TOT   450000   /* edges + self-loops */
#define NEG 0.2f
#define CAP 64           /* edge bucket capacity; deg = Poisson(8)+1, max over dataset ~27 */

typedef __attribute__((ext_vector_type(8))) short bf16x8;
typedef __attribute__((ext_vector_type(8))) unsigned short u16x8;
typedef __attribute__((ext_vector_type(4))) float f32x4;

__device__ __forceinline__ float lrelu(float x) { return x > 0.f ? x : NEG * x; }

__device__ __forceinline__ unsigned short f2bf(float f) {
    unsigned u = __float_as_uint(f);
    unsigned r = u + 0x7FFFu + ((u >> 16) & 1u);   /* RNE */
    return (unsigned short)(r >> 16);
}
__device__ __forceinline__ float bf2f(unsigned short h) {
    return __uint_as_float(((unsigned)h) << 16);
}

/* ---------------- init: weight prep (W1/W2 hi, W1a hi+lo) + cursor zero ---------------- */
__global__ void k_init(const float* __restrict__ W1, unsigned short* W1hiT,
                       const float* __restrict__ W2, unsigned short* W2hiT,
                       const float* __restrict__ a1s, const float* __restrict__ a1d,
                       unsigned short* W1aThi, unsigned short* W1aTlo,
                       int* cursor) {
    int i = blockIdx.x * 256 + threadIdx.x;
    if (i < 128 * 512) {
        int col = i & 511, k = i >> 9;
        W1hiT[col * 128 + k] = f2bf(W1[k * 512 + col]);
    } else if (i < 128 * 512 + 512 * 16) {
        int j = i - 128 * 512;
        int col = j & 15, k = j >> 4;
        W2hiT[col * 512 + k] = f2bf(W2[k * 16 + col]);
    } else if (i < 128 * 512 + 512 * 16 + 128 * 16) {
        int j = i - (128 * 512 + 512 * 16);
        int c16 = j & 15, k = j >> 4;
        int hd = c16 & 7;
        const float* av = (c16 < 8) ? a1s : a1d;
        float acc = 0.f;
#pragma unroll 8
        for (int c = 0; c < 64; c++)
            acc = fmaf(W1[k * 512 + hd * 64 + c], av[hd * 64 + c], acc);
        unsigned short h = f2bf(acc);
        W1aThi[c16 * 128 + k] = h;
        W1aTlo[c16 * 128 + k] = f2bf(acc - bf2f(h));
    } else {
        int j = i - (128 * 512 + 512 * 16 + 128 * 16);
        if (j < N_NODES) cursor[j] = 0;
    }
}

/* ---------------- merged: edge scatter-append (blocks < SCAT) + layer-1 GEMM ---------------- */
#define SCAT 256
__global__ __launch_bounds__(256) void k_sg1(const int* __restrict__ ei,
                                             int* __restrict__ cursor,
                                             int* __restrict__ colsrc,
                                             const float* __restrict__ x,
                                             const unsigned short* __restrict__ W1hiT,
                                             const unsigned short* __restrict__ W1aThi,
                                             const unsigned short* __restrict__ W1aTlo,
                                             unsigned short* __restrict__ h1b,
                                             float* __restrict__ al1s,
                                             float* __restrict__ al1d) {
    __shared__ unsigned short xs_hi[64 * 136];
    if (blockIdx.x < SCAT) {
        int gtid = blockIdx.x * 256 + threadIdx.x;
        for (int i = gtid; i < N_TOT; i += SCAT * 256) {
            int src, dst;
            if (i < N_EDGES) { src = ei[i]; dst = ei[N_EDGES + i]; }
            else             { src = dst = i - N_EDGES; }
            int pos = atomicAdd(&cursor[dst], 1);
            if (pos < CAP) colsrc[dst * CAP + pos] = src;
        }
        return;
    }
    const int t = threadIdx.x;
    const int rb = (blockIdx.x - SCAT) * 64;

#pragma unroll
    for (int i = 0; i < 8; i++) {
        int idx = t + 256 * i;           /* 2048 float4 total */
        int r = idx >> 5;                /* 32 float4 per row */
        int k = (idx & 31) * 4;
        int gr = rb + r;
        float4 v = make_float4(0.f, 0.f, 0.f, 0.f);
        if (gr < N_NODES) v = *reinterpret_cast<const float4*>(&x[gr * 128 + k]);
        ushort4 hi;
        hi.x = f2bf(v.x); hi.y = f2bf(v.y); hi.z = f2bf(v.z); hi.w = f2bf(v.w);
        *reinterpret_cast<ushort4*>(&xs_hi[r * 136 + k]) = hi;
    }
    __syncthreads();

    const int lane = t & 63;
    const int w = t >> 6;
    const int kbase = (lane >> 4) * 8;
    const int colloc = (w << 4) + (lane & 15);

#pragma unroll
    for (int pr = 0; pr < 4; pr++) {
        bf16x8 bhi[2][4];
#pragma unroll
        for (int si = 0; si < 2; si++) {
            int col = (pr * 2 + si) * 64 + colloc;
#pragma unroll
            for (int kc = 0; kc < 4; kc++)
                bhi[si][kc] = *reinterpret_cast<const bf16x8*>(&W1hiT[col * 128 + kc * 32 + kbase]);
        }
#pragma unroll
        for (int mt = 0; mt < 4; mt++) {
            const int arow = mt * 16 + (lane & 15);
            bf16x8 ah[4];
#pragma unroll
            for (int kc = 0; kc < 4; kc++)
                ah[kc] = *reinterpret_cast<const bf16x8*>(&xs_hi[arow * 136 + kc * 32 + kbase]);
#pragma unroll
            for (int si = 0; si < 2; si++) {
                f32x4 acc = {0.f, 0.f, 0.f, 0.f};
#pragma unroll
                for (int kc = 0; kc < 4; kc++)
                    acc = __builtin_amdgcn_mfma_f32_16x16x32_bf16(ah[kc], bhi[si][kc], acc, 0, 0, 0);
                const int col = (pr * 2 + si) * 64 + colloc;
                const int r0 = rb + mt * 16 + (lane >> 4) * 4;
#pragma unroll
                for (int r = 0; r < 4; r++) {
                    int row = r0 + r;
                    if (row < N_NODES) h1b[row * 512 + col] = f2bf(acc[r]);
                }
            }
        }
    }

    /* fused attention-half tile: wave w handles m-tile w, cols 0..15 of W1a (hi+lo) */
    {
        const int c16 = lane & 15;
        bf16x8 bh[4], bl[4];
#pragma unroll
        for (int kc = 0; kc < 4; kc++) {
            bh[kc] = *reinterpret_cast<const bf16x8*>(&W1aThi[c16 * 128 + kc * 32 + kbase]);
            bl[kc] = *reinterpret_cast<const bf16x8*>(&W1aTlo[c16 * 128 + kc * 32 + kbase]);
        }
        const int arow = (w << 4) + (lane & 15);
        f32x4 acc = {0.f, 0.f, 0.f, 0.f};
#pragma unroll
        for (int kc = 0; kc < 4; kc++) {
            bf16x8 ah = *reinterpret_cast<const bf16x8*>(&xs_hi[arow * 136 + kc * 32 + kbase]);
            acc = __builtin_amdgcn_mfma_f32_16x16x32_bf16(ah, bh[kc], acc, 0, 0, 0);
            acc = __builtin_amdgcn_mfma_f32_16x16x32_bf16(ah, bl[kc], acc, 0, 0, 0);
        }
        const int r0 = rb + (w << 4) + (lane >> 4) * 4;
#pragma unroll
        for (int r = 0; r < 4; r++) {
            int row = r0 + r;
            if (row < N_NODES) {
                if (c16 < 8) al1s[row * 8 + c16] = acc[r];
                else         al1d[row * 8 + (c16 - 8)] = acc[r];
            }
        }
    }
}

/* ---------------- Layer 1 softmax+agg FUSED with layer-2 GEMM ----------------
   256 thr = 4 waves; each wave handles TWO dst nodes (8 nodes/block, grid 6250
   exact). Two independent edge chains per wave (A,B) interleaved -> forced ILP:
   chain A's loads overlap chain B's FMAs regardless of compiler vmcnt choices.
   Named u16x8 buffers only (no arrays/lambdas -> no scratch, r3 lesson).
   Per-edge: one 16B load/lane; cnt padded to even (pad = row 0, weight 0).
   Epilogue: 8 finished rows -> LDS bf16, wave 0 does 8x512 @ 512x16 via MFMA
   (A rows wrapped lane&7; C rows 8-15 discarded), emits h2b + al2s/al2d. */
#define LDX(dst, s0reg, jj)                                                   \
    { int s_ = __shfl(s0reg, (jj), 64);                                       \
      dst = *reinterpret_cast<const u16x8*>(&h1b[s_ * 512 + c8]); }
#define CONSA(buf, jj)                                                        \
    { float w_ = pwA[pwh + (jj)]; smA += w_;                                  \
      _Pragma("unroll")                                                       \
      for (int c_ = 0; c_ < 8; c_++)                                          \
          accA[c_] = fmaf(w_, bf2f(buf[c_]), accA[c_]); }
#define CONSB(buf, jj)                                                        \
    { float w_ = pwB[pwh + (jj)]; smB += w_;                                  \
      _Pragma("unroll")                                                       \
      for (int c_ = 0; c_ < 8; c_++)                                          \
          accB[c_] = fmaf(w_, bf2f(buf[c_]), accB[c_]); }

__global__ __launch_bounds__(256) void k_agg1(const int* __restrict__ cursor,
                                              const int* __restrict__ colsrc,
                                              const float* __restrict__ al1s,
                                              const float* __restrict__ al1d,
                                              const unsigned short* __restrict__ h1b,
                                              const float* __restrict__ b1,
                                              const unsigned short* __restrict__ W2hiT,
                                              const float* __restrict__ a2s,
                                              const float* __restrict__ a2d,
                                              unsigned short* __restrict__ h2b,
                                              float* __restrict__ al2s,
                                              float* __restrict__ al2d) {
    __shared__ float pw[8][528];                         /* per-node edge weights [8 heads][66] */
    __shared__ __align__(16) unsigned short vs[8 * 520]; /* 8 finished h1 rows, bf16, padded */
    const int wv   = threadIdx.x >> 6;
    const int lane = threadIdx.x & 63;
    const int n0 = blockIdx.x * 8;
    const int nA = n0 + wv * 2;
    const int nB = nA + 1;
    const int cntA = min(cursor[nA], CAP);
    const int cntB = min(cursor[nB], CAP);
    const int h  = lane >> 3;
    const int c8 = lane << 3;
    const int pwh = h * 66;
    float* pwA = pw[wv * 2];
    float* pwB = pw[wv * 2 + 1];

    /* edge source ids (pad lanes keep s=0 -> row 0, weight 0) */
    int sA = 0, sB = 0;
    if (lane < cntA) sA = colsrc[nA * CAP + lane];
    if (lane < cntB) sB = colsrc[nB * CAP + lane];

    /* prefetch first two edges of each chain BEFORE the softmax math */
    u16x8 eA0, eA1, eB0, eB1;
    LDX(eA0, sA, 0); LDX(eA1, sA, 1);
    LDX(eB0, sB, 0); LDX(eB1, sB, 1);

    /* attention logits -> exp weights for both nodes */
    {
        const float4 dA0 = *reinterpret_cast<const float4*>(&al1d[nA * 8]);
        const float4 dA1 = *reinterpret_cast<const float4*>(&al1d[nA * 8 + 4]);
        const float4 dB0 = *reinterpret_cast<const float4*>(&al1d[nB * 8]);
        const float4 dB1 = *reinterpret_cast<const float4*>(&al1d[nB * 8 + 4]);
        float pA[8], pB[8];
#pragma unroll
        for (int k = 0; k < 8; k++) { pA[k] = 0.f; pB[k] = 0.f; }
        if (lane < cntA) {
            const float4 u0 = *reinterpret_cast<const float4*>(&al1s[sA * 8]);
            const float4 u1 = *reinterpret_cast<const float4*>(&al1s[sA * 8 + 4]);
            pA[0] = __expf(fminf(lrelu(u0.x + dA0.x), 60.f));
            pA[1] = __expf(fminf(lrelu(u0.y + dA0.y), 60.f));
            pA[2] = __expf(fminf(lrelu(u0.z + dA0.z), 60.f));
            pA[3] = __expf(fminf(lrelu(u0.w + dA0.w), 60.f));
            pA[4] = __expf(fminf(lrelu(u1.x + dA1.x), 60.f));
            pA[5] = __expf(fminf(lrelu(u1.y + dA1.y), 60.f));
            pA[6] = __expf(fminf(lrelu(u1.z + dA1.z), 60.f));
            pA[7] = __expf(fminf(lrelu(u1.w + dA1.w), 60.f));
        }
        if (lane < cntB) {
            const float4 u0 = *reinterpret_cast<const float4*>(&al1s[sB * 8]);
            const float4 u1 = *reinterpret_cast<const float4*>(&al1s[sB * 8 + 4]);
            pB[0] = __expf(fminf(lrelu(u0.x + dB0.x), 60.f));
            pB[1] = __expf(fminf(lrelu(u0.y + dB0.y), 60.f));
            pB[2] = __expf(fminf(lrelu(u0.z + dB0.z), 60.f));
            pB[3] = __expf(fminf(lrelu(u0.w + dB0.w), 60.f));
            pB[4] = __expf(fminf(lrelu(u1.x + dB1.x), 60.f));
            pB[5] = __expf(fminf(lrelu(u1.y + dB1.y), 60.f));
            pB[6] = __expf(fminf(lrelu(u1.z + dB1.z), 60.f));
            pB[7] = __expf(fminf(lrelu(u1.w + dB1.w), 60.f));
        }
#pragma unroll
        for (int k = 0; k < 8; k++) {
            pwA[k * 66 + lane] = pA[k];
            pwB[k * 66 + lane] = pB[k];
        }
    }

    float accA[8] = {0.f, 0.f, 0.f, 0.f, 0.f, 0.f, 0.f, 0.f};
    float accB[8] = {0.f, 0.f, 0.f, 0.f, 0.f, 0.f, 0.f, 0.f};
    float smA = 0.f, smB = 0.f;
    const int mA = (cntA + 1) & ~1;                      /* >=2 (self-loop guarantees cnt>=1) */
    const int mB = (cntB + 1) & ~1;

    int j = 0;
    while (true) {
        u16x8 tA0, tA1, tB0, tB1;
        const bool cA = (j + 2) < mA;
        const bool cB = (j + 2) < mB;
        if (cA) { LDX(tA0, sA, j + 2); LDX(tA1, sA, j + 3); }
        if (cB) { LDX(tB0, sB, j + 2); LDX(tB1, sB, j + 3); }
        if (j < mA) { CONSA(eA0, j); CONSA(eA1, j + 1); }
        if (j < mB) { CONSB(eB0, j); CONSB(eB1, j + 1); }
        if (!cA && !cB) break;
        eA0 = tA0; eA1 = tA1; eB0 = tB0; eB1 = tB1;
        j += 2;
    }

    /* normalize + bias + ELU -> vs rows 2wv (A) and 2wv+1 (B) */
    {
        const float4 ba = *reinterpret_cast<const float4*>(&b1[c8]);
        const float4 bb = *reinterpret_cast<const float4*>(&b1[c8 + 4]);
        const float invA = 1.f / smA;
        const float invB = 1.f / smB;
        float vA[8], vB[8];
        vA[0] = accA[0] * invA + ba.x; vA[1] = accA[1] * invA + ba.y;
        vA[2] = accA[2] * invA + ba.z; vA[3] = accA[3] * invA + ba.w;
        vA[4] = accA[4] * invA + bb.x; vA[5] = accA[5] * invA + bb.y;
        vA[6] = accA[6] * invA + bb.z; vA[7] = accA[7] * invA + bb.w;
        vB[0] = accB[0] * invB + ba.x; vB[1] = accB[1] * invB + ba.y;
        vB[2] = accB[2] * invB + ba.z; vB[3] = accB[3] * invB + ba.w;
        vB[4] = accB[4] * invB + bb.x; vB[5] = accB[5] * invB + bb.y;
        vB[6] = accB[6] * invB + bb.z; vB[7] = accB[7] * invB + bb.w;
#pragma unroll
        for (int k = 0; k < 8; k++) {
            vA[k] = vA[k] > 0.f ? vA[k] : __expf(vA[k]) - 1.f;
            vB[k] = vB[k] > 0.f ? vB[k] : __expf(vB[k]) - 1.f;
        }
        u16x8 oA, oB;
#pragma unroll
        for (int k = 0; k < 8; k++) { oA[k] = f2bf(vA[k]); oB[k] = f2bf(vB[k]); }
        *reinterpret_cast<u16x8*>(&vs[(wv * 2) * 520 + c8]) = oA;
        *reinterpret_cast<u16x8*>(&vs[(wv * 2 + 1) * 520 + c8]) = oB;
    }

    __syncthreads();

    if (wv == 0) {
        /* 8x512 @ 512x16 matvec for the block's 8 nodes via MFMA.
           A rows wrapped lane&7: rows 8-15 duplicate 0-7; their C rows discarded. */
        const int col   = lane & 15;
        const int kbase = (lane >> 4) << 3;
        const int rowm  = lane & 7;
        f32x4 a2 = {0.f, 0.f, 0.f, 0.f};
#pragma unroll 4
        for (int kc = 0; kc < 16; kc++) {
            bf16x8 bh = *reinterpret_cast<const bf16x8*>(&W2hiT[col * 512 + kc * 32 + kbase]);
            bf16x8 ah = *reinterpret_cast<const bf16x8*>(&vs[rowm * 520 + kc * 32 + kbase]);
            a2 = __builtin_amdgcn_mfma_f32_16x16x32_bf16(ah, bh, a2, 0, 0, 0);
        }
        /* C: row=(lane>>4)*4+r, col=lane&15 -> lanes 0-31 hold rows 0-7 (the 8 nodes) */
        if (lane < 32) {
            const float as_c = a2s[col];
            const float ad_c = a2d[col];
            const int rbase = n0 + (lane >> 4) * 4;
#pragma unroll
            for (int r = 0; r < 4; r++) {
                float ps = a2[r] * as_c;
                float pd = a2[r] * ad_c;
                ps += __shfl_xor(ps, 1, 64); pd += __shfl_xor(pd, 1, 64);
                ps += __shfl_xor(ps, 2, 64); pd += __shfl_xor(pd, 2, 64);
                ps += __shfl_xor(ps, 4, 64); pd += __shfl_xor(pd, 4, 64);
                ps += __shfl_xor(ps, 8, 64); pd += __shfl_xor(pd, 8, 64);
                h2b[(rbase + r) * 16 + col] = f2bf(a2[r]);
                if ((lane & 15) == 0) { al2s[rbase + r] = ps; al2d[rbase + r] = pd; }
            }
        }
    }
}

/* ---------------- Layer 2 aggregation -> out (8-edge-parallel, 4B h2b loads) ---------------- */
__global__ __launch_bounds__(256) void k_agg2(const int* __restrict__ cursor,
                                              const int* __restrict__ colsrc,
                                              const float* __restrict__ al2s,
                                              const float* __restrict__ al2d,
                                              const unsigned short* __restrict__ h2b,
                                              const float* __restrict__ b2,
                                              float* __restrict__ out) {
    int wv = threadIdx.x >> 6, lane = threadIdx.x & 63;
    int n = blockIdx.x * 4 + wv;
    if (n >= N_NODES) return;
    int cnt = min(cursor[n], CAP);
    const int eb = n * CAP;
    float ald = al2d[n];
    int q = lane >> 3;            /* edge slot 0..7 */
    int c2 = (lane & 7) << 1;     /* channel pair base */
    float acc0 = 0.f, acc1 = 0.f, smL = 0.f;
    for (int e = q; e < cnt; e += 8) {
        int s = colsrc[eb + e];
        float w = __expf(fminf(lrelu(al2s[s] + ald), 60.f));
        unsigned v = *reinterpret_cast<const unsigned*>(&h2b[s * 16 + c2]);
        smL += w;
        acc0 = fmaf(w, bf2f((unsigned short)(v & 0xFFFFu)), acc0);
        acc1 = fmaf(w, __uint_as_float(v & 0xFFFF0000u), acc1);
    }
    acc0 += __shfl_xor(acc0, 8, 64);  acc1 += __shfl_xor(acc1, 8, 64);  smL += __shfl_xor(smL, 8, 64);
    acc0 += __shfl_xor(acc0, 16, 64); acc1 += __shfl_xor(acc1, 16, 64); smL += __shfl_xor(smL, 16, 64);
    acc0 += __shfl_xor(acc0, 32, 64); acc1 += __shfl_xor(acc1, 32, 64); smL += __shfl_xor(smL, 32, 64);
    if (q == 0) {
        float inv = 1.f / smL;
        float2 r;
        r.x = acc0 * inv + b2[c2];
        r.y = acc1 * inv + b2[c2 + 1];
        *reinterpret_cast<float2*>(&out[n * 16 + c2]) = r;
    }
}

/* ---------------- launch ---------------- */
extern "C" void kernel_launch(void* const* d_in, const int* in_sizes, int n_in,
                              void* d_out, int out_size, void* d_ws, size_t ws_size,
                              hipStream_t stream) {
    const float* x   = (const float*)d_in[0];
    const int*   ei  = (const int*)d_in[1];
    const float* W1  = (const float*)d_in[2];
    const float* a1s = (const float*)d_in[3];
    const float* a1d = (const float*)d_in[4];
    const float* b1  = (const float*)d_in[5];
    const float* W2  = (const float*)d_in[6];
    const float* a2s = (const float*)d_in[7];
    const float* a2d = (const float*)d_in[8];
    const float* b2  = (const float*)d_in[9];
    float* out = (float*)d_out;

    char* ws = (char*)d_ws;
    unsigned short* h1b = (unsigned short*)(ws + 0);            /* N*512 bf16 = 51.2 MB */
    unsigned short* h2b = (unsigned short*)(ws + 102400000);    /* N*16 bf16 = 1.6 MB */
    float* al1s = (float*)(ws + 105600000);    /* N*8 */
    float* al1d = (float*)(ws + 107200000);    /* N*8 */
    float* al2s = (float*)(ws + 108800000);    /* N */
    float* al2d = (float*)(ws + 109000000);    /* N */
    int* cursor = (int*)(ws + 109200000);      /* N ints */
    int* colsrc = (int*)(ws + 109400000);      /* N*CAP ints = 12.8 MB */
    unsigned short* W1hiT  = (unsigned short*)(ws + 122200000); /* 512x128 bf16 */
    unsigned short* W2hiT  = (unsigned short*)(ws + 122336000); /* 16x512 bf16 */
    unsigned short* W1aThi = (unsigned short*)(ws + 122352384); /* 16x128 bf16 */
    unsigned short* W1aTlo = (unsigned short*)(ws + 122356480);

    /* init: weight prep + cursor zero (one launch) */
    k_init<<<492, 256, 0, stream>>>(W1, W1hiT, W2, W2hiT, a1s, a1d, W1aThi, W1aTlo, cursor);

    /* scatter-append + layer-1 GEMM (merged) */
    k_sg1<<<SCAT + (N_NODES + 63) / 64, 256, 0, stream>>>(ei, cursor, colsrc, x,
                                                          W1hiT, W1aThi, W1aTlo,
                                                          h1b, al1s, al1d);

    /* layer 1 aggregation fused with layer-2 GEMM (2 nodes/wave, dual chains) */
    k_agg1<<<N_NODES / 8, 256, 0, stream>>>(cursor, colsrc, al1s, al1d, h1b, b1,
                                            W2hiT, a2s, a2d, h2b, al2s, al2d);

    /* layer 2 aggregation */
    k_agg2<<<(N_NODES + 3) / 4, 256, 0, stream>>>(cursor, colsrc, al2s, al2d, h2b, b2, out);
}